// Round 11
// baseline (327.051 us; speedup 1.0000x reference)
//
#include <hip/hip_runtime.h>

typedef unsigned short u16;
typedef __attribute__((ext_vector_type(8))) short v8s;
typedef __attribute__((ext_vector_type(4))) short v4s;
typedef __attribute__((ext_vector_type(4))) float v4f;
typedef __attribute__((ext_vector_type(2))) unsigned int v2u;

#define MFMA32(a, b, c) __builtin_amdgcn_mfma_f32_16x16x32_bf16(a, b, c, 0, 0, 0)

// raw v_exp_f32 (2^x) — skips libm fixup code
#if __has_builtin(__builtin_amdgcn_exp2f)
#define EXP2(x) __builtin_amdgcn_exp2f(x)
#else
#define EXP2(x) exp2f(x)
#endif

// K=16 bf16 MFMA: builtin name is the legacy gfx90a "_1k" spelling on ROCm.
// Fallback (always-correct): zero-pad both frags to 8 elems and use K=32.
#if __has_builtin(__builtin_amdgcn_mfma_f32_16x16x16bf16_1k)
static __device__ __forceinline__ v4f mfma16(v4s a, v4s b, v4f c) {
    return __builtin_amdgcn_mfma_f32_16x16x16bf16_1k(a, b, c, 0, 0, 0);
}
#else
static __device__ __forceinline__ v4f mfma16(v4s a, v4s b, v4f c) {
    v4s z = {0, 0, 0, 0};
    v8s a8 = __builtin_shufflevector(a, z, 0, 1, 2, 3, 4, 5, 6, 7);
    v8s b8 = __builtin_shufflevector(b, z, 0, 1, 2, 3, 4, 5, 6, 7);
    return MFMA32(a8, b8, c);
}
#endif

static __device__ __forceinline__ u16 f32_to_bf16(float f) {
    unsigned int u = __builtin_bit_cast(unsigned int, f);
    u += 0x7fffu + ((u >> 16) & 1u);     // RNE
    return (u16)(u >> 16);
}
static __device__ __forceinline__ v8s cvt8(v4f lo, v4f hi) {
    v8s r;
#pragma unroll
    for (int i = 0; i < 4; i++) {
        r[i]     = (short)f32_to_bf16(lo[i]);
        r[i + 4] = (short)f32_to_bf16(hi[i]);
    }
    return r;
}

// cheap packed f32->bf16, round-half-up (differs from RNE only at exact
// ties, <=1 ulp): 1 integer add per elem + 1 v_perm_b32 per pair.
// (harness-proven in R6)
static __device__ __forceinline__ v4s pack4(float a, float b, float c, float d) {
    const unsigned int ua = __builtin_bit_cast(unsigned int, a) + 0x8000u;
    const unsigned int ub = __builtin_bit_cast(unsigned int, b) + 0x8000u;
    const unsigned int uc = __builtin_bit_cast(unsigned int, c) + 0x8000u;
    const unsigned int ud = __builtin_bit_cast(unsigned int, d) + 0x8000u;
    // perm(src0=hiWord, src1=loWord, 0x07060302): bytes {s1[2],s1[3],s0[2],s0[3]}
    v2u t = {__builtin_amdgcn_perm(ub, ua, 0x07060302u),
             __builtin_amdgcn_perm(ud, uc, 0x07060302u)};
    return __builtin_bit_cast(v4s, t);
}

// async global->LDS, 16 B/lane. LDS dest is wave-uniform base + lane*16
// (rule #21: keep BOTH sides linear).
static __device__ __forceinline__ void gld16(const u16* g, u16* l) {
    __builtin_amdgcn_global_load_lds(
        (const __attribute__((address_space(1))) void*)g,
        (__attribute__((address_space(3))) void*)l, 16, 0, 0);
}

// ---------------------------------------------------------------------------
// 32x32 tiled transpose f32 -> bf16 (weights only; tiny)
// ---------------------------------------------------------------------------
__global__ void transpose_f32_bf16(const float* __restrict__ in,
                                   u16* __restrict__ out, int R, int C) {
    __shared__ u16 t[32][33];
    const int tid = threadIdx.x;
    const int tx = tid & 31, ty = tid >> 5;
    const int c0 = blockIdx.x * 32, r0 = blockIdx.y * 32;
#pragma unroll
    for (int i = 0; i < 32; i += 8)
        t[ty + i][tx] = f32_to_bf16(in[(size_t)(r0 + ty + i) * C + c0 + tx]);
    __syncthreads();
#pragma unroll
    for (int i = 0; i < 32; i += 8)
        out[(size_t)(c0 + ty + i) * R + r0 + tx] = t[tx][ty + i];
}

// ---------------------------------------------------------------------------
// GEMM, manual reg staging, LDS stride 72 (odd granules -> conflict-free).
// QKV slot: R7-measured 110 µs (AMODE=1, f32 A, cvt on load).
// ---------------------------------------------------------------------------
template <int AMODE, int CMODE>
__global__ __launch_bounds__(256)
void gemm_bt(const void* __restrict__ A, int lda,
             const u16* __restrict__ Bt, int ldb,
             const float* __restrict__ bias,
             void* __restrict__ Cq, u16* __restrict__ Kb, u16* __restrict__ VtG,
             int ldc, int K) {
    __shared__ __align__(16) u16 As[128 * 72];
    __shared__ __align__(16) u16 Bs[128 * 72];

    const int tid  = threadIdx.x;
    const int wid  = tid >> 6;
    const int lane = tid & 63;
    const int l15  = lane & 15;
    const int quad = lane >> 4;
    const int bm = blockIdx.y * 128;
    const int bn = blockIdx.x * 128;
    const int wm = (wid & 1) * 64;
    const int wn = (wid >> 1) * 64;

    const int sr = tid >> 3;          // 0..31 (rows +0,32,64,96)
    const int sg = (tid & 7) * 8;     // 0..56

    const float* Af = (const float*)A;
    const u16*   Au = (const u16*)A;

    v4f acc[4][4];
#pragma unroll
    for (int i = 0; i < 4; i++)
#pragma unroll
        for (int j = 0; j < 4; j++) acc[i][j] = (v4f)0.f;

    for (int kb = 0; kb < K; kb += 64) {
        v8s a[4], b[4];
#pragma unroll
        for (int i = 0; i < 4; i++) {
            const int row = sr + i * 32;
            if (AMODE) {
                const float* p = Af + (size_t)(bm + row) * lda + kb + sg;
                a[i] = cvt8(*(const v4f*)p, *(const v4f*)(p + 4));
            } else {
                a[i] = *(const v8s*)(Au + (size_t)(bm + row) * lda + kb + sg);
            }
            b[i] = *(const v8s*)(Bt + (size_t)(bn + row) * ldb + kb + sg);
        }
        __syncthreads();   // previous iteration's LDS reads complete
#pragma unroll
        for (int i = 0; i < 4; i++) {
            const int row = sr + i * 32;
            *(v8s*)&As[row * 72 + sg] = a[i];
            *(v8s*)&Bs[row * 72 + sg] = b[i];
        }
        __syncthreads();

        v8s af[2][4], bf[2][4];
#pragma unroll
        for (int ko = 0; ko < 2; ko++) {
#pragma unroll
            for (int mt = 0; mt < 4; mt++)
                af[ko][mt] = *(const v8s*)&As[(wm + mt * 16 + l15) * 72 + ko * 32 + quad * 8];
#pragma unroll
            for (int nt = 0; nt < 4; nt++)
                bf[ko][nt] = *(const v8s*)&Bs[(wn + nt * 16 + l15) * 72 + ko * 32 + quad * 8];
        }
#pragma unroll
        for (int ko = 0; ko < 2; ko++)
#pragma unroll
            for (int mt = 0; mt < 4; mt++)
#pragma unroll
                for (int nt = 0; nt < 4; nt++)
                    acc[mt][nt] = MFMA32(af[ko][mt], bf[ko][nt], acc[mt][nt]);
    }

    // epilogue: C-layout col=lane&15, row=quad*4+reg
#pragma unroll
    for (int nt = 0; nt < 4; nt++) {
        const int n = bn + wn + nt * 16 + l15;
        const float bv = bias[n];
#pragma unroll
        for (int mt = 0; mt < 4; mt++) {
#pragma unroll
            for (int r = 0; r < 4; r++) {
                const int m = bm + wm + mt * 16 + quad * 4 + r;
                const float val = acc[mt][nt][r] + bv;
                if (CMODE == 1) {
                    ((float*)Cq)[(size_t)m * ldc + n] = val;
                } else {
                    const int region = n >> 10, nl = n & 1023;
                    // fold softmax scale (0.125*log2e) into Q, in f32
                    const float sv = (region == 0) ? val * 0.18033688f : val;
                    const u16 o = f32_to_bf16(sv);
                    if (region == 0) {
                        ((u16*)Cq)[(size_t)m * 1024 + nl] = o;
                    } else if (region == 1) {
                        Kb[(size_t)m * 1024 + nl] = o;
                    } else {
                        const int h = nl >> 6, dh = nl & 63;
                        const int b = m >> 11, s = m & 2047;
                        VtG[((size_t)((b * 16 + h) * 64 + dh)) * 2048 + s] = o;
                    }
                }
            }
        }
    }
}

// ---------------------------------------------------------------------------
// GEMM (bf16 A), 2-phase issue-early double-buffer + global_load_lds.
// R10 measured: SLOWER than gemm_bt in the QKV slot (136 vs 110, vmcnt(0)
// drain defeats the pipeline) but FASTER in the out-proj slot (~36 µs net
// vs R7 — only 512 blocks there, B L2-resident). Used for out-proj only.
// ---------------------------------------------------------------------------
template <int CMODE>
__global__ __launch_bounds__(256)
void gemm_gld(const u16* __restrict__ A, int lda,
              const u16* __restrict__ Bt, int ldb,
              const float* __restrict__ bias,
              void* __restrict__ Cq, u16* __restrict__ Kb, u16* __restrict__ VtG,
              int ldc, int K) {
    __shared__ __align__(16) u16 As[2][128 * 64];
    __shared__ __align__(16) u16 Bs[2][128 * 64];

    const int tid  = threadIdx.x;
    const int wid  = tid >> 6;
    const int lane = tid & 63;
    const int l15  = lane & 15;
    const int quad = lane >> 4;
    const int bm = blockIdx.y * 128;
    const int bn = blockIdx.x * 128;
    const int wm = (wid & 1) * 64;
    const int wn = (wid >> 1) * 64;

    const int srow = lane >> 3;        // 0..7
    const int scol = (lane & 7) * 8;   // 0..56 u16

    v4f acc[4][4];
#pragma unroll
    for (int i = 0; i < 4; i++)
#pragma unroll
        for (int j = 0; j < 4; j++) acc[i][j] = (v4f)0.f;

    auto STAGE = [&](int buf, int kb) {
#pragma unroll
        for (int r = 0; r < 4; r++) {
            const int row0 = r * 32 + wid * 8;            // wave-uniform
            gld16(A  + (size_t)(bm + row0 + srow) * lda + kb + scol, &As[buf][row0 * 64]);
            gld16(Bt + (size_t)(bn + row0 + srow) * ldb + kb + scol, &Bs[buf][row0 * 64]);
        }
    };

    const int NT = K >> 6;
    STAGE(0, 0);
    __syncthreads();                   // buf0 ready (drains vmcnt)

    int cur = 0;
    for (int t = 0; t < NT; ++t) {
        if (t + 1 < NT) STAGE(cur ^ 1, (t + 1) << 6);  // async, in flight

        v8s af[2][4], bf[2][4];
#pragma unroll
        for (int ko = 0; ko < 2; ko++) {
#pragma unroll
            for (int mt = 0; mt < 4; mt++)
                af[ko][mt] = *(const v8s*)&As[cur][(wm + mt * 16 + l15) * 64 + ko * 32 + quad * 8];
#pragma unroll
            for (int nt = 0; nt < 4; nt++)
                bf[ko][nt] = *(const v8s*)&Bs[cur][(wn + nt * 16 + l15) * 64 + ko * 32 + quad * 8];
        }
#pragma unroll
        for (int ko = 0; ko < 2; ko++)
#pragma unroll
            for (int mt = 0; mt < 4; mt++)
#pragma unroll
                for (int nt = 0; nt < 4; nt++)
                    acc[mt][nt] = MFMA32(af[ko][mt], bf[ko][nt], acc[mt][nt]);

        __syncthreads();   // drains staged loads + all reads of cur
        cur ^= 1;
    }

    // epilogue: C-layout col=lane&15, row=quad*4+reg
#pragma unroll
    for (int nt = 0; nt < 4; nt++) {
        const int n = bn + wn + nt * 16 + l15;
        const float bv = bias[n];
#pragma unroll
        for (int mt = 0; mt < 4; mt++) {
#pragma unroll
            for (int r = 0; r < 4; r++) {
                const int m = bm + wm + mt * 16 + quad * 4 + r;
                const float val = acc[mt][nt][r] + bv;
                if (CMODE == 1) {
                    ((float*)Cq)[(size_t)m * ldc + n] = val;
                } else {
                    const int region = n >> 10, nl = n & 1023;
                    const float sv = (region == 0) ? val * 0.18033688f : val;
                    const u16 o = f32_to_bf16(sv);
                    if (region == 0) {
                        ((u16*)Cq)[(size_t)m * 1024 + nl] = o;
                    } else if (region == 1) {
                        Kb[(size_t)m * 1024 + nl] = o;
                    } else {
                        const int h = nl >> 6, dh = nl & 63;
                        const int b = m >> 11, s = m & 2047;
                        VtG[((size_t)((b * 16 + h) * 64 + dh)) * 2048 + s] = o;
                    }
                }
            }
        }
    }
}

// ---------------------------------------------------------------------------
// Flash attention, register-direct P feed (harness-proven R7 version,
// unchanged: scale pre-folded in Q, l on MFMA pipe via ones-frag, raw exp2).
// ---------------------------------------------------------------------------
__global__ __launch_bounds__(256)
void attn_fused(u16* __restrict__ Qb, const u16* __restrict__ Kb,
                const u16* __restrict__ VtG) {
    __shared__ __align__(16) u16 Ks[64 * 72];      // [key][dh]
    __shared__ __align__(16) u16 Vs[64 * 72];      // [dh][key]

    const int tid  = threadIdx.x;
    const int wid  = tid >> 6;
    const int lane = tid & 63;
    const int l15  = lane & 15;
    const int quad = lane >> 4;
    const int qt = blockIdx.x;
    const int h  = blockIdx.y;
    const int bz = blockIdx.z;

    const size_t qbase = (size_t)bz * 2048 * 1024;
    const int q0 = qt * 128 + wid * 32;

    v8s aq[2][2];
#pragma unroll
    for (int qh = 0; qh < 2; qh++) {
        const u16* qrow = Qb + qbase + (size_t)(q0 + qh * 16 + l15) * 1024 + h * 64 + quad * 8;
        aq[qh][0] = *(const v8s*)qrow;
        aq[qh][1] = *(const v8s*)(qrow + 32);
    }

    v4f accO[2][4];                   // [qh][dh-tile]: O^T[dh=c*16+quad*4+r][q=l15]
    v4f accL[2];                      // [qh]: all rows equal = l[q=l15]
#pragma unroll
    for (int qh = 0; qh < 2; qh++) {
        accL[qh] = (v4f)0.f;
#pragma unroll
        for (int c = 0; c < 4; c++) accO[qh][c] = (v4f)0.f;
    }
    const v4s ones = {(short)0x3F80, (short)0x3F80, (short)0x3F80, (short)0x3F80};

    const int sr = tid >> 3;          // 0..31 (rows +0, +32)
    const int sg = (tid & 7) * 8;     // 0..56

    const u16* kpb = Kb + qbase + h * 64;
    const u16* vpb = VtG + (size_t)((bz * 16 + h) * 64) * 2048;

    for (int kt = 0; kt < 32; kt++) {
        const v8s k0 = *(const v8s*)(kpb + (size_t)(kt * 64 + sr) * 1024 + sg);
        const v8s k1 = *(const v8s*)(kpb + (size_t)(kt * 64 + sr + 32) * 1024 + sg);
        const v8s v0 = *(const v8s*)(vpb + (size_t)sr * 2048 + kt * 64 + sg);
        const v8s v1 = *(const v8s*)(vpb + (size_t)(sr + 32) * 2048 + kt * 64 + sg);
        __syncthreads();
        *(v8s*)&Ks[sr * 72 + sg]        = k0;
        *(v8s*)&Ks[(sr + 32) * 72 + sg] = k1;
        *(v8s*)&Vs[sr * 72 + sg]        = v0;
        *(v8s*)&Vs[(sr + 32) * 72 + sg] = v1;
        __syncthreads();

#pragma unroll
        for (int kc = 0; kc < 4; kc++) {
            // K A-frags (shared across q-subtiles)
            const v8s kf0 = *(const v8s*)&Ks[(kc * 16 + l15) * 72 + quad * 8];
            const v8s kf1 = *(const v8s*)&Ks[(kc * 16 + l15) * 72 + 32 + quad * 8];
            // V^T A-frags for the 4 dh-tiles (shared across q-subtiles)
            v4s vf[4];
#pragma unroll
            for (int c = 0; c < 4; c++)
                vf[c] = *(const v4s*)&Vs[(c * 16 + l15) * 72 + kc * 16 + quad * 4];

#pragma unroll
            for (int qh = 0; qh < 2; qh++) {
                v4f st = (v4f)0.f;
                st = MFMA32(kf0, aq[qh][0], st);   // A=K (m=key), B=Q (n=q)
                st = MFMA32(kf1, aq[qh][1], st);
                const float p0 = EXP2(st[0]);      // scale pre-folded into Q
                const float p1 = EXP2(st[1]);
                const float p2 = EXP2(st[2]);
                const float p3 = EXP2(st[3]);
                const v4s pk = pack4(p0, p1, p2, p3);
                // l += sum_k P[k][q] on the MFMA pipe (ones-row trick)
                accL[qh] = mfma16(ones, pk, accL[qh]);
                // O^T += V^T * P^T, P fed straight from registers
#pragma unroll
                for (int c = 0; c < 4; c++)
                    accO[qh][c] = mfma16(vf[c], pk, accO[qh][c]);
            }
        }
    }

    // epilogue: lane's q = l15 (its own row), l already lane-local in accL
#pragma unroll
    for (int qh = 0; qh < 2; qh++) {
        const int q = q0 + qh * 16 + l15;
        const float inv = 1.f / accL[qh][0];
#pragma unroll
        for (int c = 0; c < 4; c++) {
            const v4s o = pack4(accO[qh][c][0] * inv, accO[qh][c][1] * inv,
                                accO[qh][c][2] * inv, accO[qh][c][3] * inv);
            *(v4s*)&Qb[qbase + (size_t)q * 1024 + h * 64 + c * 16 + quad * 4] = o;
        }
    }
}

// ---------------------------------------------------------------------------
extern "C" void kernel_launch(void* const* d_in, const int* in_sizes, int n_in,
                              void* d_out, int out_size, void* d_ws, size_t ws_size,
                              hipStream_t stream) {
    (void)in_sizes; (void)n_in; (void)out_size;
    const float* x    = (const float*)d_in[0];
    const float* wqkv = (const float*)d_in[1];
    const float* bqkv = (const float*)d_in[2];
    const float* wout = (const float*)d_in[3];
    const float* bout = (const float*)d_in[4];
    float* outp = (float*)d_out;

    char* ws = (char*)d_ws;
    const size_t BIG  = 58720256;    // 56 MiB (known working)

    if (ws_size >= BIG || ws_size == 0) {
        u16* Qb    = (u16*)(ws);                 // 16 MiB
        u16* Kb    = (u16*)(ws + 16777216);      // 16 MiB
        u16* VtG   = (u16*)(ws + 33554432);      // 16 MiB
        u16* wqkvT = (u16*)(ws + 50331648);      // 6 MiB
        u16* woutT = (u16*)(ws + 56623104);      // 2 MiB

        transpose_f32_bf16<<<dim3(96, 32), 256, 0, stream>>>(wqkv, wqkvT, 1024, 3072);
        transpose_f32_bf16<<<dim3(32, 32), 256, 0, stream>>>(wout, woutT, 1024, 1024);
        gemm_bt<1, 2><<<dim3(24, 64), 256, 0, stream>>>(
            x, 1024, wqkvT, 1024, bqkv, Qb, Kb, VtG, 0, 1024);
        attn_fused<<<dim3(16, 16, 4), 256, 0, stream>>>(Qb, Kb, VtG);
        gemm_gld<1><<<dim3(8, 64), 256, 0, stream>>>(
            Qb, 1024, woutT, 1024, bout, outp, nullptr, nullptr, 1024, 1024);
    } else {
        // small-ws path (20 MiB): per-batch, proven gemm_bt
        u16* wqkvT = (u16*)(ws);                 // 6 MiB
        u16* woutT = (u16*)(ws + 6291456);       // 2 MiB
        u16* Qb    = (u16*)(ws + 8388608);       // 4 MiB
        u16* Kb    = (u16*)(ws + 12582912);      // 4 MiB
        u16* VtG   = (u16*)(ws + 16777216);      // 4 MiB

        transpose_f32_bf16<<<dim3(96, 32), 256, 0, stream>>>(wqkv, wqkvT, 1024, 3072);
        transpose_f32_bf16<<<dim3(32, 32), 256, 0, stream>>>(wout, woutT, 1024, 1024);
        for (int b = 0; b < 4; b++) {
            const float* xb = x + (size_t)b * 2048 * 1024;
            float* ob = outp + (size_t)b * 2048 * 1024;
            gemm_bt<1, 2><<<dim3(24, 16), 256, 0, stream>>>(
                xb, 1024, wqkvT, 1024, bqkv, Qb, Kb, VtG, 0, 1024);
            attn_fused<<<dim3(16, 16, 1), 256, 0, stream>>>(Qb, Kb, VtG);
            gemm_bt<0, 1><<<dim3(8, 16), 256, 0, stream>>>(
                Qb, 1024, woutT, 1024, bout, ob, nullptr, nullptr, 1024, 1024);
        }
    }
}

// Round 12
// 313.627 us; speedup vs baseline: 1.0428x; 1.0428x over previous
//
#include <hip/hip_runtime.h>

typedef unsigned short u16;
typedef __attribute__((ext_vector_type(8))) short v8s;
typedef __attribute__((ext_vector_type(4))) short v4s;
typedef __attribute__((ext_vector_type(4))) float v4f;
typedef __attribute__((ext_vector_type(2))) unsigned int v2u;

#define MFMA32(a, b, c) __builtin_amdgcn_mfma_f32_16x16x32_bf16(a, b, c, 0, 0, 0)

// raw v_exp_f32 (2^x) — skips libm fixup code
#if __has_builtin(__builtin_amdgcn_exp2f)
#define EXP2(x) __builtin_amdgcn_exp2f(x)
#else
#define EXP2(x) exp2f(x)
#endif

// K=16 bf16 MFMA: builtin name is the legacy gfx90a "_1k" spelling on ROCm.
// Fallback (always-correct): zero-pad both frags to 8 elems and use K=32.
#if __has_builtin(__builtin_amdgcn_mfma_f32_16x16x16bf16_1k)
static __device__ __forceinline__ v4f mfma16(v4s a, v4s b, v4f c) {
    return __builtin_amdgcn_mfma_f32_16x16x16bf16_1k(a, b, c, 0, 0, 0);
}
#else
static __device__ __forceinline__ v4f mfma16(v4s a, v4s b, v4f c) {
    v4s z = {0, 0, 0, 0};
    v8s a8 = __builtin_shufflevector(a, z, 0, 1, 2, 3, 4, 5, 6, 7);
    v8s b8 = __builtin_shufflevector(b, z, 0, 1, 2, 3, 4, 5, 6, 7);
    return MFMA32(a8, b8, c);
}
#endif

static __device__ __forceinline__ u16 f32_to_bf16(float f) {
    unsigned int u = __builtin_bit_cast(unsigned int, f);
    u += 0x7fffu + ((u >> 16) & 1u);     // RNE
    return (u16)(u >> 16);
}
static __device__ __forceinline__ v8s cvt8(v4f lo, v4f hi) {
    v8s r;
#pragma unroll
    for (int i = 0; i < 4; i++) {
        r[i]     = (short)f32_to_bf16(lo[i]);
        r[i + 4] = (short)f32_to_bf16(hi[i]);
    }
    return r;
}

// cheap packed f32->bf16, round-half-up (differs from RNE only at exact
// ties, <=1 ulp): 1 integer add per elem + 1 v_perm_b32 per pair.
// (harness-proven in R6)
static __device__ __forceinline__ v4s pack4(float a, float b, float c, float d) {
    const unsigned int ua = __builtin_bit_cast(unsigned int, a) + 0x8000u;
    const unsigned int ub = __builtin_bit_cast(unsigned int, b) + 0x8000u;
    const unsigned int uc = __builtin_bit_cast(unsigned int, c) + 0x8000u;
    const unsigned int ud = __builtin_bit_cast(unsigned int, d) + 0x8000u;
    // perm(src0=hiWord, src1=loWord, 0x07060302): bytes {s1[2],s1[3],s0[2],s0[3]}
    v2u t = {__builtin_amdgcn_perm(ub, ua, 0x07060302u),
             __builtin_amdgcn_perm(ud, uc, 0x07060302u)};
    return __builtin_bit_cast(v4s, t);
}

// async global->LDS, 16 B/lane. LDS dest is wave-uniform base + lane*16
// (rule #21: keep BOTH sides linear).
static __device__ __forceinline__ void gld16(const u16* g, u16* l) {
    __builtin_amdgcn_global_load_lds(
        (const __attribute__((address_space(1))) void*)g,
        (__attribute__((address_space(3))) void*)l, 16, 0, 0);
}

// ---------------------------------------------------------------------------
// f32 -> bf16 cast, 8 elems/thread
// ---------------------------------------------------------------------------
__global__ void cast_f32_bf16(const float* __restrict__ in,
                              u16* __restrict__ out, int n8) {
    const int i = blockIdx.x * blockDim.x + threadIdx.x;
    if (i < n8) {
        v4f lo = ((const v4f*)in)[2 * i];
        v4f hi = ((const v4f*)in)[2 * i + 1];
        ((v8s*)out)[i] = cvt8(lo, hi);
    }
}

// ---------------------------------------------------------------------------
// 32x32 tiled transpose f32 -> bf16 (weights only; tiny)
// ---------------------------------------------------------------------------
__global__ void transpose_f32_bf16(const float* __restrict__ in,
                                   u16* __restrict__ out, int R, int C) {
    __shared__ u16 t[32][33];
    const int tid = threadIdx.x;
    const int tx = tid & 31, ty = tid >> 5;
    const int c0 = blockIdx.x * 32, r0 = blockIdx.y * 32;
#pragma unroll
    for (int i = 0; i < 32; i += 8)
        t[ty + i][tx] = f32_to_bf16(in[(size_t)(r0 + ty + i) * C + c0 + tx]);
    __syncthreads();
#pragma unroll
    for (int i = 0; i < 32; i += 8)
        out[(size_t)(c0 + ty + i) * R + r0 + tx] = t[tx][ty + i];
}

// ---------------------------------------------------------------------------
// GEMM, manual reg staging, LDS stride 72 (odd granules -> conflict-free).
// QKV slot with AMODE=0 (bf16 A): R7-measured 110 µs, FETCH 76 MB, VGPR 104.
// AMODE=1 (f32 A) measured 128 µs / FETCH 145 MB (R11) — bf16 precast wins.
// ---------------------------------------------------------------------------
template <int AMODE, int CMODE>
__global__ __launch_bounds__(256)
void gemm_bt(const void* __restrict__ A, int lda,
             const u16* __restrict__ Bt, int ldb,
             const float* __restrict__ bias,
             void* __restrict__ Cq, u16* __restrict__ Kb, u16* __restrict__ VtG,
             int ldc, int K) {
    __shared__ __align__(16) u16 As[128 * 72];
    __shared__ __align__(16) u16 Bs[128 * 72];

    const int tid  = threadIdx.x;
    const int wid  = tid >> 6;
    const int lane = tid & 63;
    const int l15  = lane & 15;
    const int quad = lane >> 4;
    const int bm = blockIdx.y * 128;
    const int bn = blockIdx.x * 128;
    const int wm = (wid & 1) * 64;
    const int wn = (wid >> 1) * 64;

    const int sr = tid >> 3;          // 0..31 (rows +0,32,64,96)
    const int sg = (tid & 7) * 8;     // 0..56

    const float* Af = (const float*)A;
    const u16*   Au = (const u16*)A;

    v4f acc[4][4];
#pragma unroll
    for (int i = 0; i < 4; i++)
#pragma unroll
        for (int j = 0; j < 4; j++) acc[i][j] = (v4f)0.f;

    for (int kb = 0; kb < K; kb += 64) {
        v8s a[4], b[4];
#pragma unroll
        for (int i = 0; i < 4; i++) {
            const int row = sr + i * 32;
            if (AMODE) {
                const float* p = Af + (size_t)(bm + row) * lda + kb + sg;
                a[i] = cvt8(*(const v4f*)p, *(const v4f*)(p + 4));
            } else {
                a[i] = *(const v8s*)(Au + (size_t)(bm + row) * lda + kb + sg);
            }
            b[i] = *(const v8s*)(Bt + (size_t)(bn + row) * ldb + kb + sg);
        }
        __syncthreads();   // previous iteration's LDS reads complete
#pragma unroll
        for (int i = 0; i < 4; i++) {
            const int row = sr + i * 32;
            *(v8s*)&As[row * 72 + sg] = a[i];
            *(v8s*)&Bs[row * 72 + sg] = b[i];
        }
        __syncthreads();

        v8s af[2][4], bf[2][4];
#pragma unroll
        for (int ko = 0; ko < 2; ko++) {
#pragma unroll
            for (int mt = 0; mt < 4; mt++)
                af[ko][mt] = *(const v8s*)&As[(wm + mt * 16 + l15) * 72 + ko * 32 + quad * 8];
#pragma unroll
            for (int nt = 0; nt < 4; nt++)
                bf[ko][nt] = *(const v8s*)&Bs[(wn + nt * 16 + l15) * 72 + ko * 32 + quad * 8];
        }
#pragma unroll
        for (int ko = 0; ko < 2; ko++)
#pragma unroll
            for (int mt = 0; mt < 4; mt++)
#pragma unroll
                for (int nt = 0; nt < 4; nt++)
                    acc[mt][nt] = MFMA32(af[ko][mt], bf[ko][nt], acc[mt][nt]);
    }

    // epilogue: C-layout col=lane&15, row=quad*4+reg
#pragma unroll
    for (int nt = 0; nt < 4; nt++) {
        const int n = bn + wn + nt * 16 + l15;
        const float bv = bias[n];
#pragma unroll
        for (int mt = 0; mt < 4; mt++) {
#pragma unroll
            for (int r = 0; r < 4; r++) {
                const int m = bm + wm + mt * 16 + quad * 4 + r;
                const float val = acc[mt][nt][r] + bv;
                if (CMODE == 1) {
                    ((float*)Cq)[(size_t)m * ldc + n] = val;
                } else {
                    const int region = n >> 10, nl = n & 1023;
                    // fold softmax scale (0.125*log2e) into Q, in f32
                    const float sv = (region == 0) ? val * 0.18033688f : val;
                    const u16 o = f32_to_bf16(sv);
                    if (region == 0) {
                        ((u16*)Cq)[(size_t)m * 1024 + nl] = o;
                    } else if (region == 1) {
                        Kb[(size_t)m * 1024 + nl] = o;
                    } else {
                        const int h = nl >> 6, dh = nl & 63;
                        const int b = m >> 11, s = m & 2047;
                        VtG[((size_t)((b * 16 + h) * 64 + dh)) * 2048 + s] = o;
                    }
                }
            }
        }
    }
}

// ---------------------------------------------------------------------------
// GEMM (bf16 A), 2-phase issue-early double-buffer + global_load_lds.
// R10/R11 measured: out-proj slot winner (~45 µs; 512 blocks, B L2-resident).
// NOT used for QKV (R10: 136 µs there — vmcnt(0) drain + occupancy loss).
// ---------------------------------------------------------------------------
template <int CMODE>
__global__ __launch_bounds__(256)
void gemm_gld(const u16* __restrict__ A, int lda,
              const u16* __restrict__ Bt, int ldb,
              const float* __restrict__ bias,
              void* __restrict__ Cq, u16* __restrict__ Kb, u16* __restrict__ VtG,
              int ldc, int K) {
    __shared__ __align__(16) u16 As[2][128 * 64];
    __shared__ __align__(16) u16 Bs[2][128 * 64];

    const int tid  = threadIdx.x;
    const int wid  = tid >> 6;
    const int lane = tid & 63;
    const int l15  = lane & 15;
    const int quad = lane >> 4;
    const int bm = blockIdx.y * 128;
    const int bn = blockIdx.x * 128;
    const int wm = (wid & 1) * 64;
    const int wn = (wid >> 1) * 64;

    const int srow = lane >> 3;        // 0..7
    const int scol = (lane & 7) * 8;   // 0..56 u16

    v4f acc[4][4];
#pragma unroll
    for (int i = 0; i < 4; i++)
#pragma unroll
        for (int j = 0; j < 4; j++) acc[i][j] = (v4f)0.f;

    auto STAGE = [&](int buf, int kb) {
#pragma unroll
        for (int r = 0; r < 4; r++) {
            const int row0 = r * 32 + wid * 8;            // wave-uniform
            gld16(A  + (size_t)(bm + row0 + srow) * lda + kb + scol, &As[buf][row0 * 64]);
            gld16(Bt + (size_t)(bn + row0 + srow) * ldb + kb + scol, &Bs[buf][row0 * 64]);
        }
    };

    const int NT = K >> 6;
    STAGE(0, 0);
    __syncthreads();                   // buf0 ready (drains vmcnt)

    int cur = 0;
    for (int t = 0; t < NT; ++t) {
        if (t + 1 < NT) STAGE(cur ^ 1, (t + 1) << 6);  // async, in flight

        v8s af[2][4], bf[2][4];
#pragma unroll
        for (int ko = 0; ko < 2; ko++) {
#pragma unroll
            for (int mt = 0; mt < 4; mt++)
                af[ko][mt] = *(const v8s*)&As[cur][(wm + mt * 16 + l15) * 64 + ko * 32 + quad * 8];
#pragma unroll
            for (int nt = 0; nt < 4; nt++)
                bf[ko][nt] = *(const v8s*)&Bs[cur][(wn + nt * 16 + l15) * 64 + ko * 32 + quad * 8];
        }
#pragma unroll
        for (int ko = 0; ko < 2; ko++)
#pragma unroll
            for (int mt = 0; mt < 4; mt++)
#pragma unroll
                for (int nt = 0; nt < 4; nt++)
                    acc[mt][nt] = MFMA32(af[ko][mt], bf[ko][nt], acc[mt][nt]);

        __syncthreads();   // drains staged loads + all reads of cur
        cur ^= 1;
    }

    // epilogue: C-layout col=lane&15, row=quad*4+reg
#pragma unroll
    for (int nt = 0; nt < 4; nt++) {
        const int n = bn + wn + nt * 16 + l15;
        const float bv = bias[n];
#pragma unroll
        for (int mt = 0; mt < 4; mt++) {
#pragma unroll
            for (int r = 0; r < 4; r++) {
                const int m = bm + wm + mt * 16 + quad * 4 + r;
                const float val = acc[mt][nt][r] + bv;
                if (CMODE == 1) {
                    ((float*)Cq)[(size_t)m * ldc + n] = val;
                } else {
                    const int region = n >> 10, nl = n & 1023;
                    const float sv = (region == 0) ? val * 0.18033688f : val;
                    const u16 o = f32_to_bf16(sv);
                    if (region == 0) {
                        ((u16*)Cq)[(size_t)m * 1024 + nl] = o;
                    } else if (region == 1) {
                        Kb[(size_t)m * 1024 + nl] = o;
                    } else {
                        const int h = nl >> 6, dh = nl & 63;
                        const int b = m >> 11, s = m & 2047;
                        VtG[((size_t)((b * 16 + h) * 64 + dh)) * 2048 + s] = o;
                    }
                }
            }
        }
    }
}

// ---------------------------------------------------------------------------
// Flash attention, register-direct P feed (harness-proven R7 version,
// unchanged: scale pre-folded in Q, l on MFMA pipe via ones-frag, raw exp2).
// ---------------------------------------------------------------------------
__global__ __launch_bounds__(256)
void attn_fused(u16* __restrict__ Qb, const u16* __restrict__ Kb,
                const u16* __restrict__ VtG) {
    __shared__ __align__(16) u16 Ks[64 * 72];      // [key][dh]
    __shared__ __align__(16) u16 Vs[64 * 72];      // [dh][key]

    const int tid  = threadIdx.x;
    const int wid  = tid >> 6;
    const int lane = tid & 63;
    const int l15  = lane & 15;
    const int quad = lane >> 4;
    const int qt = blockIdx.x;
    const int h  = blockIdx.y;
    const int bz = blockIdx.z;

    const size_t qbase = (size_t)bz * 2048 * 1024;
    const int q0 = qt * 128 + wid * 32;

    v8s aq[2][2];
#pragma unroll
    for (int qh = 0; qh < 2; qh++) {
        const u16* qrow = Qb + qbase + (size_t)(q0 + qh * 16 + l15) * 1024 + h * 64 + quad * 8;
        aq[qh][0] = *(const v8s*)qrow;
        aq[qh][1] = *(const v8s*)(qrow + 32);
    }

    v4f accO[2][4];                   // [qh][dh-tile]: O^T[dh=c*16+quad*4+r][q=l15]
    v4f accL[2];                      // [qh]: all rows equal = l[q=l15]
#pragma unroll
    for (int qh = 0; qh < 2; qh++) {
        accL[qh] = (v4f)0.f;
#pragma unroll
        for (int c = 0; c < 4; c++) accO[qh][c] = (v4f)0.f;
    }
    const v4s ones = {(short)0x3F80, (short)0x3F80, (short)0x3F80, (short)0x3F80};

    const int sr = tid >> 3;          // 0..31 (rows +0, +32)
    const int sg = (tid & 7) * 8;     // 0..56

    const u16* kpb = Kb + qbase + h * 64;
    const u16* vpb = VtG + (size_t)((bz * 16 + h) * 64) * 2048;

    for (int kt = 0; kt < 32; kt++) {
        const v8s k0 = *(const v8s*)(kpb + (size_t)(kt * 64 + sr) * 1024 + sg);
        const v8s k1 = *(const v8s*)(kpb + (size_t)(kt * 64 + sr + 32) * 1024 + sg);
        const v8s v0 = *(const v8s*)(vpb + (size_t)sr * 2048 + kt * 64 + sg);
        const v8s v1 = *(const v8s*)(vpb + (size_t)(sr + 32) * 2048 + kt * 64 + sg);
        __syncthreads();
        *(v8s*)&Ks[sr * 72 + sg]        = k0;
        *(v8s*)&Ks[(sr + 32) * 72 + sg] = k1;
        *(v8s*)&Vs[sr * 72 + sg]        = v0;
        *(v8s*)&Vs[(sr + 32) * 72 + sg] = v1;
        __syncthreads();

#pragma unroll
        for (int kc = 0; kc < 4; kc++) {
            // K A-frags (shared across q-subtiles)
            const v8s kf0 = *(const v8s*)&Ks[(kc * 16 + l15) * 72 + quad * 8];
            const v8s kf1 = *(const v8s*)&Ks[(kc * 16 + l15) * 72 + 32 + quad * 8];
            // V^T A-frags for the 4 dh-tiles (shared across q-subtiles)
            v4s vf[4];
#pragma unroll
            for (int c = 0; c < 4; c++)
                vf[c] = *(const v4s*)&Vs[(c * 16 + l15) * 72 + kc * 16 + quad * 4];

#pragma unroll
            for (int qh = 0; qh < 2; qh++) {
                v4f st = (v4f)0.f;
                st = MFMA32(kf0, aq[qh][0], st);   // A=K (m=key), B=Q (n=q)
                st = MFMA32(kf1, aq[qh][1], st);
                const float p0 = EXP2(st[0]);      // scale pre-folded into Q
                const float p1 = EXP2(st[1]);
                const float p2 = EXP2(st[2]);
                const float p3 = EXP2(st[3]);
                const v4s pk = pack4(p0, p1, p2, p3);
                // l += sum_k P[k][q] on the MFMA pipe (ones-row trick)
                accL[qh] = mfma16(ones, pk, accL[qh]);
                // O^T += V^T * P^T, P fed straight from registers
#pragma unroll
                for (int c = 0; c < 4; c++)
                    accO[qh][c] = mfma16(vf[c], pk, accO[qh][c]);
            }
        }
    }

    // epilogue: lane's q = l15 (its own row), l already lane-local in accL
#pragma unroll
    for (int qh = 0; qh < 2; qh++) {
        const int q = q0 + qh * 16 + l15;
        const float inv = 1.f / accL[qh][0];
#pragma unroll
        for (int c = 0; c < 4; c++) {
            const v4s o = pack4(accO[qh][c][0] * inv, accO[qh][c][1] * inv,
                                accO[qh][c][2] * inv, accO[qh][c][3] * inv);
            *(v4s*)&Qb[qbase + (size_t)q * 1024 + h * 64 + c * 16 + quad * 4] = o;
        }
    }
}

// ---------------------------------------------------------------------------
extern "C" void kernel_launch(void* const* d_in, const int* in_sizes, int n_in,
                              void* d_out, int out_size, void* d_ws, size_t ws_size,
                              hipStream_t stream) {
    (void)in_sizes; (void)n_in; (void)out_size;
    const float* x    = (const float*)d_in[0];
    const float* wqkv = (const float*)d_in[1];
    const float* bqkv = (const float*)d_in[2];
    const float* wout = (const float*)d_in[3];
    const float* bout = (const float*)d_in[4];
    float* outp = (float*)d_out;

    char* ws = (char*)d_ws;
    const size_t BIG  = 58720256;    // 56 MiB (known working)

    if (ws_size >= BIG || ws_size == 0) {
        u16* Qb    = (u16*)(ws);                 // 16 MiB
        u16* Kb    = (u16*)(ws + 16777216);      // 16 MiB
        u16* VtG   = (u16*)(ws + 33554432);      // 16 MiB
        u16* wqkvT = (u16*)(ws + 50331648);      // 6 MiB
        u16* woutT = (u16*)(ws + 56623104);      // 2 MiB
        // bf16 precast of x in the FIRST 16 MiB of d_out (32 MiB f32):
        // consumed by the QKV GEMM, then overwritten by the out-projection.
        // (placement harness-proven in R9/R10)
        u16* xb    = (u16*)outp;

        transpose_f32_bf16<<<dim3(96, 32), 256, 0, stream>>>(wqkv, wqkvT, 1024, 3072);
        transpose_f32_bf16<<<dim3(32, 32), 256, 0, stream>>>(wout, woutT, 1024, 1024);
        cast_f32_bf16<<<4096, 256, 0, stream>>>(x, xb, 1048576);
        gemm_bt<0, 2><<<dim3(24, 64), 256, 0, stream>>>(
            xb, 1024, wqkvT, 1024, bqkv, Qb, Kb, VtG, 0, 1024);
        attn_fused<<<dim3(16, 16, 4), 256, 0, stream>>>(Qb, Kb, VtG);
        gemm_gld<1><<<dim3(8, 64), 256, 0, stream>>>(
            Qb, 1024, woutT, 1024, bout, outp, nullptr, nullptr, 1024, 1024);
    } else {
        // small-ws path (20 MiB): per-batch, proven gemm_bt
        u16* wqkvT = (u16*)(ws);                 // 6 MiB
        u16* woutT = (u16*)(ws + 6291456);       // 2 MiB
        u16* Qb    = (u16*)(ws + 8388608);       // 4 MiB
        u16* Kb    = (u16*)(ws + 12582912);      // 4 MiB
        u16* VtG   = (u16*)(ws + 16777216);      // 4 MiB

        transpose_f32_bf16<<<dim3(96, 32), 256, 0, stream>>>(wqkv, wqkvT, 1024, 3072);
        transpose_f32_bf16<<<dim3(32, 32), 256, 0, stream>>>(wout, woutT, 1024, 1024);
        for (int b = 0; b < 4; b++) {
            const float* xb = x + (size_t)b * 2048 * 1024;
            float* ob = outp + (size_t)b * 2048 * 1024;
            gemm_bt<1, 2><<<dim3(24, 16), 256, 0, stream>>>(
                xb, 1024, wqkvT, 1024, bqkv, Qb, Kb, VtG, 0, 1024);
            attn_fused<<<dim3(16, 16, 1), 256, 0, stream>>>(Qb, Kb, VtG);
            gemm_bt<0, 1><<<dim3(8, 16), 256, 0, stream>>>(
                Qb, 1024, woutT, 1024, bout, ob, nullptr, nullptr, 1024, 1024);
        }
    }
}

// Round 14
// 304.499 us; speedup vs baseline: 1.0741x; 1.0300x over previous
//
#include <hip/hip_runtime.h>

typedef unsigned short u16;
typedef __attribute__((ext_vector_type(8))) short v8s;
typedef __attribute__((ext_vector_type(4))) short v4s;
typedef __attribute__((ext_vector_type(4))) float v4f;
typedef __attribute__((ext_vector_type(2))) unsigned int v2u;

#define MFMA32(a, b, c) __builtin_amdgcn_mfma_f32_16x16x32_bf16(a, b, c, 0, 0, 0)

// raw v_exp_f32 (2^x) — skips libm fixup code
#if __has_builtin(__builtin_amdgcn_exp2f)
#define EXP2(x) __builtin_amdgcn_exp2f(x)
#else
#define EXP2(x) exp2f(x)
#endif

// K=16 bf16 MFMA: builtin name is the legacy gfx90a "_1k" spelling on ROCm.
// Fallback (always-correct): zero-pad both frags to 8 elems and use K=32.
#if __has_builtin(__builtin_amdgcn_mfma_f32_16x16x16bf16_1k)
static __device__ __forceinline__ v4f mfma16(v4s a, v4s b, v4f c) {
    return __builtin_amdgcn_mfma_f32_16x16x16bf16_1k(a, b, c, 0, 0, 0);
}
#else
static __device__ __forceinline__ v4f mfma16(v4s a, v4s b, v4f c) {
    v4s z = {0, 0, 0, 0};
    v8s a8 = __builtin_shufflevector(a, z, 0, 1, 2, 3, 4, 5, 6, 7);
    v8s b8 = __builtin_shufflevector(b, z, 0, 1, 2, 3, 4, 5, 6, 7);
    return MFMA32(a8, b8, c);
}
#endif

static __device__ __forceinline__ u16 f32_to_bf16(float f) {
    unsigned int u = __builtin_bit_cast(unsigned int, f);
    u += 0x7fffu + ((u >> 16) & 1u);     // RNE
    return (u16)(u >> 16);
}
static __device__ __forceinline__ v8s cvt8(v4f lo, v4f hi) {
    v8s r;
#pragma unroll
    for (int i = 0; i < 4; i++) {
        r[i]     = (short)f32_to_bf16(lo[i]);
        r[i + 4] = (short)f32_to_bf16(hi[i]);
    }
    return r;
}

// cheap packed f32->bf16, round-half-up (harness-proven in R6)
static __device__ __forceinline__ v4s pack4(float a, float b, float c, float d) {
    const unsigned int ua = __builtin_bit_cast(unsigned int, a) + 0x8000u;
    const unsigned int ub = __builtin_bit_cast(unsigned int, b) + 0x8000u;
    const unsigned int uc = __builtin_bit_cast(unsigned int, c) + 0x8000u;
    const unsigned int ud = __builtin_bit_cast(unsigned int, d) + 0x8000u;
    v2u t = {__builtin_amdgcn_perm(ub, ua, 0x07060302u),
             __builtin_amdgcn_perm(ud, uc, 0x07060302u)};
    return __builtin_bit_cast(v4s, t);
}

// async global->LDS, 16 B/lane. LDS dest is wave-uniform base + lane*16
// (rule #21: keep BOTH sides linear; swizzling done on the global source).
static __device__ __forceinline__ void gld16(const u16* g, u16* l) {
    __builtin_amdgcn_global_load_lds(
        (const __attribute__((address_space(1))) void*)g,
        (__attribute__((address_space(3))) void*)l, 16, 0, 0);
}

// raw barrier + scheduling fence: sched_barrier(0) right after s_barrier
// prevents the compiler from hoisting any op (esp. ds_read) above the
// barrier — rule #18: bare s_barrier is NOT a compile-time fence.
static __device__ __forceinline__ void barrier_fenced() {
    __builtin_amdgcn_s_barrier();
    __builtin_amdgcn_sched_barrier(0);
}

// ---------------------------------------------------------------------------
// f32 -> bf16 cast, 8 elems/thread
// ---------------------------------------------------------------------------
__global__ void cast_f32_bf16(const float* __restrict__ in,
                              u16* __restrict__ out, int n8) {
    const int i = blockIdx.x * blockDim.x + threadIdx.x;
    if (i < n8) {
        v4f lo = ((const v4f*)in)[2 * i];
        v4f hi = ((const v4f*)in)[2 * i + 1];
        ((v8s*)out)[i] = cvt8(lo, hi);
    }
}

// ---------------------------------------------------------------------------
// 32x32 tiled transpose f32 -> bf16 (weights only; tiny)
// ---------------------------------------------------------------------------
__global__ void transpose_f32_bf16(const float* __restrict__ in,
                                   u16* __restrict__ out, int R, int C) {
    __shared__ u16 t[32][33];
    const int tid = threadIdx.x;
    const int tx = tid & 31, ty = tid >> 5;
    const int c0 = blockIdx.x * 32, r0 = blockIdx.y * 32;
#pragma unroll
    for (int i = 0; i < 32; i += 8)
        t[ty + i][tx] = f32_to_bf16(in[(size_t)(r0 + ty + i) * C + c0 + tx]);
    __syncthreads();
#pragma unroll
    for (int i = 0; i < 32; i += 8)
        out[(size_t)(c0 + ty + i) * R + r0 + tx] = t[tx][ty + i];
}

// ---------------------------------------------------------------------------
// GEMM, manual reg staging, LDS stride 72 — small-ws fallback path only.
// ---------------------------------------------------------------------------
template <int AMODE, int CMODE>
__global__ __launch_bounds__(256)
void gemm_bt(const void* __restrict__ A, int lda,
             const u16* __restrict__ Bt, int ldb,
             const float* __restrict__ bias,
             void* __restrict__ Cq, u16* __restrict__ Kb, u16* __restrict__ VtG,
             int ldc, int K) {
    __shared__ __align__(16) u16 As[128 * 72];
    __shared__ __align__(16) u16 Bs[128 * 72];

    const int tid  = threadIdx.x;
    const int wid  = tid >> 6;
    const int lane = tid & 63;
    const int l15  = lane & 15;
    const int quad = lane >> 4;
    const int bm = blockIdx.y * 128;
    const int bn = blockIdx.x * 128;
    const int wm = (wid & 1) * 64;
    const int wn = (wid >> 1) * 64;

    const int sr = tid >> 3;          // 0..31 (rows +0,32,64,96)
    const int sg = (tid & 7) * 8;     // 0..56

    const float* Af = (const float*)A;
    const u16*   Au = (const u16*)A;

    v4f acc[4][4];
#pragma unroll
    for (int i = 0; i < 4; i++)
#pragma unroll
        for (int j = 0; j < 4; j++) acc[i][j] = (v4f)0.f;

    for (int kb = 0; kb < K; kb += 64) {
        v8s a[4], b[4];
#pragma unroll
        for (int i = 0; i < 4; i++) {
            const int row = sr + i * 32;
            if (AMODE) {
                const float* p = Af + (size_t)(bm + row) * lda + kb + sg;
                a[i] = cvt8(*(const v4f*)p, *(const v4f*)(p + 4));
            } else {
                a[i] = *(const v8s*)(Au + (size_t)(bm + row) * lda + kb + sg);
            }
            b[i] = *(const v8s*)(Bt + (size_t)(bn + row) * ldb + kb + sg);
        }
        __syncthreads();
#pragma unroll
        for (int i = 0; i < 4; i++) {
            const int row = sr + i * 32;
            *(v8s*)&As[row * 72 + sg] = a[i];
            *(v8s*)&Bs[row * 72 + sg] = b[i];
        }
        __syncthreads();

        v8s af[2][4], bf[2][4];
#pragma unroll
        for (int ko = 0; ko < 2; ko++) {
#pragma unroll
            for (int mt = 0; mt < 4; mt++)
                af[ko][mt] = *(const v8s*)&As[(wm + mt * 16 + l15) * 72 + ko * 32 + quad * 8];
#pragma unroll
            for (int nt = 0; nt < 4; nt++)
                bf[ko][nt] = *(const v8s*)&Bs[(wn + nt * 16 + l15) * 72 + ko * 32 + quad * 8];
        }
#pragma unroll
        for (int ko = 0; ko < 2; ko++)
#pragma unroll
            for (int mt = 0; mt < 4; mt++)
#pragma unroll
                for (int nt = 0; nt < 4; nt++)
                    acc[mt][nt] = MFMA32(af[ko][mt], bf[ko][nt], acc[mt][nt]);
    }

#pragma unroll
    for (int nt = 0; nt < 4; nt++) {
        const int n = bn + wn + nt * 16 + l15;
        const float bv = bias[n];
#pragma unroll
        for (int mt = 0; mt < 4; mt++) {
#pragma unroll
            for (int r = 0; r < 4; r++) {
                const int m = bm + wm + mt * 16 + quad * 4 + r;
                const float val = acc[mt][nt][r] + bv;
                if (CMODE == 1) {
                    ((float*)Cq)[(size_t)m * ldc + n] = val;
                } else {
                    const int region = n >> 10, nl = n & 1023;
                    const float sv = (region == 0) ? val * 0.18033688f : val;
                    const u16 o = f32_to_bf16(sv);
                    if (region == 0) {
                        ((u16*)Cq)[(size_t)m * 1024 + nl] = o;
                    } else if (region == 1) {
                        Kb[(size_t)m * 1024 + nl] = o;
                    } else {
                        const int h = nl >> 6, dh = nl & 63;
                        const int b = m >> 11, s = m & 2047;
                        VtG[((size_t)((b * 16 + h) * 64 + dh)) * 2048 + s] = o;
                    }
                }
            }
        }
    }
}

// ---------------------------------------------------------------------------
// GEMM (bf16 A): 2-phase dbuf + T4 counted-vmcnt + T2 source-swizzle.
// R14 fix vs R13 (replay-race): every raw s_barrier is now followed by
// sched_barrier(0) so no ds_read can be compile-time-hoisted above the
// barrier into the window where other waves' DMAs haven't landed.
// ---------------------------------------------------------------------------
template <int CMODE>
__global__ __launch_bounds__(256)
void gemm_gld(const u16* __restrict__ A, int lda,
              const u16* __restrict__ Bt, int ldb,
              const float* __restrict__ bias,
              void* __restrict__ Cq, u16* __restrict__ Kb, u16* __restrict__ VtG,
              int ldc, int K) {
    __shared__ __align__(16) u16 As[2][128 * 64];
    __shared__ __align__(16) u16 Bs[2][128 * 64];

    const int tid  = threadIdx.x;
    const int wid  = tid >> 6;
    const int lane = tid & 63;
    const int l15  = lane & 15;
    const int quad = lane >> 4;
    const int bm = blockIdx.y * 128;
    const int bn = blockIdx.x * 128;
    const int wm = (wid & 1) * 64;
    const int wn = (wid >> 1) * 64;

    const int srow = lane >> 3;                 // 0..7
    const int sgr  = (lane & 7) ^ srow;         // swizzled source granule
    const int scol = sgr * 8;                   // u16 offset of source granule

    v4f acc[4][4];
#pragma unroll
    for (int i = 0; i < 4; i++)
#pragma unroll
        for (int j = 0; j < 4; j++) acc[i][j] = (v4f)0.f;

    // lane L writes LDS slot (row0+L/8, granule L&7); content = global
    // granule (L&7)^(row&7). row0 multiple of 8 -> row&7 = srow.
    auto STAGE = [&](int buf, int kb) {
#pragma unroll
        for (int r = 0; r < 4; r++) {
            const int row0 = r * 32 + wid * 8;            // wave-uniform
            gld16(A  + (size_t)(bm + row0 + srow) * lda + kb + scol, &As[buf][row0 * 64]);
            gld16(Bt + (size_t)(bn + row0 + srow) * ldb + kb + scol, &Bs[buf][row0 * 64]);
        }
    };

    const int NT = K >> 6;
    STAGE(0, 0);
    asm volatile("s_waitcnt vmcnt(0)" ::: "memory");
    barrier_fenced();

    const int rsw = l15 & 7;                    // read-side row&7
    int cur = 0;
    for (int t = 0; t < NT; ++t) {
        if (t + 1 < NT) {
            STAGE(cur ^ 1, (t + 1) << 6);       // async: 8 more in flight
            asm volatile("s_waitcnt vmcnt(8)" ::: "memory");  // cur's done
        } else {
            asm volatile("s_waitcnt vmcnt(0)" ::: "memory");
        }
        barrier_fenced();                       // all waves' cur landed

        v8s af[2][4], bf[2][4];
#pragma unroll
        for (int ko = 0; ko < 2; ko++) {
            const int g = ((ko * 4 + quad) ^ rsw) * 8;   // swizzled granule
#pragma unroll
            for (int mt = 0; mt < 4; mt++)
                af[ko][mt] = *(const v8s*)&As[cur][(wm + mt * 16 + l15) * 64 + g];
#pragma unroll
            for (int nt = 0; nt < 4; nt++)
                bf[ko][nt] = *(const v8s*)&Bs[cur][(wn + nt * 16 + l15) * 64 + g];
        }
#pragma unroll
        for (int ko = 0; ko < 2; ko++)
#pragma unroll
            for (int mt = 0; mt < 4; mt++)
#pragma unroll
                for (int nt = 0; nt < 4; nt++)
                    acc[mt][nt] = MFMA32(af[ko][mt], bf[ko][nt], acc[mt][nt]);

        asm volatile("s_waitcnt lgkmcnt(0)" ::: "memory");  // my reads done
        barrier_fenced();                       // all waves done reading cur
        cur ^= 1;
    }

    // epilogue: C-layout col=lane&15, row=quad*4+reg
#pragma unroll
    for (int nt = 0; nt < 4; nt++) {
        const int n = bn + wn + nt * 16 + l15;
        const float bv = bias[n];
#pragma unroll
        for (int mt = 0; mt < 4; mt++) {
#pragma unroll
            for (int r = 0; r < 4; r++) {
                const int m = bm + wm + mt * 16 + quad * 4 + r;
                const float val = acc[mt][nt][r] + bv;
                if (CMODE == 1) {
                    ((float*)Cq)[(size_t)m * ldc + n] = val;
                } else {
                    const int region = n >> 10, nl = n & 1023;
                    const float sv = (region == 0) ? val * 0.18033688f : val;
                    const u16 o = f32_to_bf16(sv);
                    if (region == 0) {
                        ((u16*)Cq)[(size_t)m * 1024 + nl] = o;
                    } else if (region == 1) {
                        Kb[(size_t)m * 1024 + nl] = o;
                    } else {
                        const int h = nl >> 6, dh = nl & 63;
                        const int b = m >> 11, s = m & 2047;
                        VtG[((size_t)((b * 16 + h) * 64 + dh)) * 2048 + s] = o;
                    }
                }
            }
        }
    }
}

// ---------------------------------------------------------------------------
// Flash attention, register-direct P feed (harness-proven R7 version).
// ---------------------------------------------------------------------------
__global__ __launch_bounds__(256)
void attn_fused(u16* __restrict__ Qb, const u16* __restrict__ Kb,
                const u16* __restrict__ VtG) {
    __shared__ __align__(16) u16 Ks[64 * 72];      // [key][dh]
    __shared__ __align__(16) u16 Vs[64 * 72];      // [dh][key]

    const int tid  = threadIdx.x;
    const int wid  = tid >> 6;
    const int lane = tid & 63;
    const int l15  = lane & 15;
    const int quad = lane >> 4;
    const int qt = blockIdx.x;
    const int h  = blockIdx.y;
    const int bz = blockIdx.z;

    const size_t qbase = (size_t)bz * 2048 * 1024;
    const int q0 = qt * 128 + wid * 32;

    v8s aq[2][2];
#pragma unroll
    for (int qh = 0; qh < 2; qh++) {
        const u16* qrow = Qb + qbase + (size_t)(q0 + qh * 16 + l15) * 1024 + h * 64 + quad * 8;
        aq[qh][0] = *(const v8s*)qrow;
        aq[qh][1] = *(const v8s*)(qrow + 32);
    }

    v4f accO[2][4];
    v4f accL[2];
#pragma unroll
    for (int qh = 0; qh < 2; qh++) {
        accL[qh] = (v4f)0.f;
#pragma unroll
        for (int c = 0; c < 4; c++) accO[qh][c] = (v4f)0.f;
    }
    const v4s ones = {(short)0x3F80, (short)0x3F80, (short)0x3F80, (short)0x3F80};

    const int sr = tid >> 3;
    const int sg = (tid & 7) * 8;

    const u16* kpb = Kb + qbase + h * 64;
    const u16* vpb = VtG + (size_t)((bz * 16 + h) * 64) * 2048;

    for (int kt = 0; kt < 32; kt++) {
        const v8s k0 = *(const v8s*)(kpb + (size_t)(kt * 64 + sr) * 1024 + sg);
        const v8s k1 = *(const v8s*)(kpb + (size_t)(kt * 64 + sr + 32) * 1024 + sg);
        const v8s v0 = *(const v8s*)(vpb + (size_t)sr * 2048 + kt * 64 + sg);
        const v8s v1 = *(const v8s*)(vpb + (size_t)(sr + 32) * 2048 + kt * 64 + sg);
        __syncthreads();
        *(v8s*)&Ks[sr * 72 + sg]        = k0;
        *(v8s*)&Ks[(sr + 32) * 72 + sg] = k1;
        *(v8s*)&Vs[sr * 72 + sg]        = v0;
        *(v8s*)&Vs[(sr + 32) * 72 + sg] = v1;
        __syncthreads();

#pragma unroll
        for (int kc = 0; kc < 4; kc++) {
            const v8s kf0 = *(const v8s*)&Ks[(kc * 16 + l15) * 72 + quad * 8];
            const v8s kf1 = *(const v8s*)&Ks[(kc * 16 + l15) * 72 + 32 + quad * 8];
            v4s vf[4];
#pragma unroll
            for (int c = 0; c < 4; c++)
                vf[c] = *(const v4s*)&Vs[(c * 16 + l15) * 72 + kc * 16 + quad * 4];

#pragma unroll
            for (int qh = 0; qh < 2; qh++) {
                v4f st = (v4f)0.f;
                st = MFMA32(kf0, aq[qh][0], st);
                st = MFMA32(kf1, aq[qh][1], st);
                const float p0 = EXP2(st[0]);
                const float p1 = EXP2(st[1]);
                const float p2 = EXP2(st[2]);
                const float p3 = EXP2(st[3]);
                const v4s pk = pack4(p0, p1, p2, p3);
                accL[qh] = mfma16(ones, pk, accL[qh]);
#pragma unroll
                for (int c = 0; c < 4; c++)
                    accO[qh][c] = mfma16(vf[c], pk, accO[qh][c]);
            }
        }
    }

#pragma unroll
    for (int qh = 0; qh < 2; qh++) {
        const int q = q0 + qh * 16 + l15;
        const float inv = 1.f / accL[qh][0];
#pragma unroll
        for (int c = 0; c < 4; c++) {
            const v4s o = pack4(accO[qh][c][0] * inv, accO[qh][c][1] * inv,
                                accO[qh][c][2] * inv, accO[qh][c][3] * inv);
            *(v4s*)&Qb[qbase + (size_t)q * 1024 + h * 64 + c * 16 + quad * 4] = o;
        }
    }
}

// ---------------------------------------------------------------------------
extern "C" void kernel_launch(void* const* d_in, const int* in_sizes, int n_in,
                              void* d_out, int out_size, void* d_ws, size_t ws_size,
                              hipStream_t stream) {
    (void)in_sizes; (void)n_in; (void)out_size;
    const float* x    = (const float*)d_in[0];
    const float* wqkv = (const float*)d_in[1];
    const float* bqkv = (const float*)d_in[2];
    const float* wout = (const float*)d_in[3];
    const float* bout = (const float*)d_in[4];
    float* outp = (float*)d_out;

    char* ws = (char*)d_ws;
    const size_t BIG  = 58720256;    // 56 MiB (known working)

    if (ws_size >= BIG || ws_size == 0) {
        u16* Qb    = (u16*)(ws);                 // 16 MiB
        u16* Kb    = (u16*)(ws + 16777216);      // 16 MiB
        u16* VtG   = (u16*)(ws + 33554432);      // 16 MiB
        u16* wqkvT = (u16*)(ws + 50331648);      // 6 MiB
        u16* woutT = (u16*)(ws + 56623104);      // 2 MiB
        // bf16 precast of x in the FIRST 16 MiB of d_out (harness-proven
        // placement, R9-R12): consumed by QKV GEMM, overwritten by out-proj.
        u16* xb    = (u16*)outp;

        transpose_f32_bf16<<<dim3(96, 32), 256, 0, stream>>>(wqkv, wqkvT, 1024, 3072);
        transpose_f32_bf16<<<dim3(32, 32), 256, 0, stream>>>(wout, woutT, 1024, 1024);
        cast_f32_bf16<<<4096, 256, 0, stream>>>(x, xb, 1048576);
        gemm_gld<2><<<dim3(24, 64), 256, 0, stream>>>(
            xb, 1024, wqkvT, 1024, bqkv, Qb, Kb, VtG, 0, 1024);
        attn_fused<<<dim3(16, 16, 4), 256, 0, stream>>>(Qb, Kb, VtG);
        gemm_gld<1><<<dim3(8, 64), 256, 0, stream>>>(
            Qb, 1024, woutT, 1024, bout, outp, nullptr, nullptr, 1024, 1024);
    } else {
        // small-ws path (20 MiB): per-batch, proven gemm_bt
        u16* wqkvT = (u16*)(ws);                 // 6 MiB
        u16* woutT = (u16*)(ws + 6291456);       // 2 MiB
        u16* Qb    = (u16*)(ws + 8388608);       // 4 MiB
        u16* Kb    = (u16*)(ws + 12582912);      // 4 MiB
        u16* VtG   = (u16*)(ws + 16777216);      // 4 MiB

        transpose_f32_bf16<<<dim3(96, 32), 256, 0, stream>>>(wqkv, wqkvT, 1024, 3072);
        transpose_f32_bf16<<<dim3(32, 32), 256, 0, stream>>>(wout, woutT, 1024, 1024);
        for (int b = 0; b < 4; b++) {
            const float* xb = x + (size_t)b * 2048 * 1024;
            float* ob = outp + (size_t)b * 2048 * 1024;
            gemm_bt<1, 2><<<dim3(24, 16), 256, 0, stream>>>(
                xb, 1024, wqkvT, 1024, bqkv, Qb, Kb, VtG, 0, 1024);
            attn_fused<<<dim3(16, 16, 1), 256, 0, stream>>>(Qb, Kb, VtG);
            gemm_bt<0, 1><<<dim3(8, 16), 256, 0, stream>>>(
                Qb, 1024, woutT, 1024, bout, ob, nullptr, nullptr, 1024, 1024);
        }
    }
}